// Round 12
// baseline (227.315 us; speedup 1.0000x reference)
//
#include <hip/hip_runtime.h>
#include <cstdint>
#include <cstddef>

#define S_LEN 4096
#define DMODEL 1024
#define NHEADS 16
#define HDK 64
#define DKV 256
#define NTOT 1536  // 1024 Q + 256 K + 256 V packed N
// SCALE * log2(e), folded into Q projection epilogue so softmax is exp2(s)
#define QSCALE 0.18033688011112042f

typedef __bf16 bf16;
typedef __bf16 bf16x8 __attribute__((ext_vector_type(8)));
typedef float f32x4 __attribute__((ext_vector_type(4)));

typedef __attribute__((address_space(3))) void lds_void;
typedef const __attribute__((address_space(1))) void gbl_void;

// async global->LDS, 16B/lane, dest = wave-uniform base + lane*16
__device__ __forceinline__ void gload16(const void* g, void* l) {
  __builtin_amdgcn_global_load_lds((gbl_void*)g, (lds_void*)l, 16, 0, 0);
}

// ---------------- fused prep: weight transposes + x downconvert + mask ----------------
__global__ __launch_bounds__(256) void prep(
    const float* __restrict__ x, const int* __restrict__ mask,
    const float* __restrict__ Wq, const float* __restrict__ Wk,
    const float* __restrict__ Wv, const float* __restrict__ Wo,
    bf16* __restrict__ xb, float* __restrict__ mkf, bf16* __restrict__ mkb,
    bf16* __restrict__ Wqt, bf16* __restrict__ Wkt,
    bf16* __restrict__ Wvt, bf16* __restrict__ Wot) {
  const int z = blockIdx.z;
  if (z < 4) {
    const float* src;
    bf16* dst;
    int C;
    switch (z) {
      case 0: src = Wq; dst = Wqt; C = DMODEL; break;
      case 1: src = Wk; dst = Wkt; C = DKV; break;
      case 2: src = Wv; dst = Wvt; C = DKV; break;
      default: src = Wo; dst = Wot; C = DMODEL; break;
    }
    const int c0 = blockIdx.x * 32;
    if (c0 >= C) return;
    __shared__ float tile[32][33];
    const int tx = threadIdx.x & 31;
    const int ty = threadIdx.x >> 5;
    const int r0 = blockIdx.y * 32;
#pragma unroll
    for (int i = 0; i < 4; i++)
      tile[ty + i * 8][tx] = src[(size_t)(r0 + ty + i * 8) * C + c0 + tx];
    __syncthreads();
#pragma unroll
    for (int i = 0; i < 4; i++)
      dst[(size_t)(c0 + ty + i * 8) * DMODEL + r0 + tx] = (bf16)tile[tx][ty + i * 8];
  } else {
    const int b = blockIdx.y * 32 + blockIdx.x;           // 0..1023
    const int half = z - 4;                               // 0 or 1
    const int i = ((half * 1024 + b) * 256 + (int)threadIdx.x) * 8;
    float4 a = *(const float4*)(x + i);
    float4 c = *(const float4*)(x + i + 4);
    bf16 o[8] = {(bf16)a.x, (bf16)a.y, (bf16)a.z, (bf16)a.w,
                 (bf16)c.x, (bf16)c.y, (bf16)c.z, (bf16)c.w};
    *(uint4*)(xb + i) = *(uint4*)o;
    if (half == 1 && b < 2) {
      const int mi = (b * 256 + (int)threadIdx.x) * 8;
#pragma unroll
      for (int j = 0; j < 8; j++) {
        float keep = mask[mi + j] ? 0.0f : 1.0f;
        mkf[mi + j] = keep;
        mkb[mi + j] = (bf16)keep;
      }
    }
  }
}

// ---------------- GEMM: 64x128 tile, BK=64, async DMA, XCD-aware scheduling ----------------
// V-region output is transposed through LDS (Bs reuse) -> coalesced 16B stores
// (the old direct Vtb[n*4096+m] path was 2B-per-lane scattered).
template <int QKV>
__global__ __launch_bounds__(256) void gemm_ld(
    const bf16* __restrict__ A, const bf16* __restrict__ Bt, int M, int N, int K,
    int NT,  // n-tile count = N/128
    const float* __restrict__ bq, const float* __restrict__ bk,
    const float* __restrict__ bv, const float* __restrict__ mkf,
    bf16* __restrict__ Qb, bf16* __restrict__ Kb, bf16* __restrict__ Vtb,
    const float* __restrict__ bo, float* __restrict__ Co) {
  __shared__ bf16 As[64 * 64];
  __shared__ bf16 Bs[128 * 64];
  const int t = threadIdx.x;
  const int lane = t & 63;
  const int wave = t >> 6;

  // XCD-aware decode: xcd = bid&7 (round-robin dispatch heuristic)
  const int bid = blockIdx.x;
  const int xcd = bid & 7;
  const int local = bid >> 3;
  const int m_local = local / NT;
  const int ntile = local - m_local * NT;
  const int mchunk = (M >> 6) >> 3;  // m-tiles per XCD
  const int m0 = (xcd * mchunk + m_local) * 64;
  const int n0 = ntile * 128;

  const int wm = (wave >> 1) * 32;
  const int wn = (wave & 1) * 64;
  const int lr = lane & 15;
  const int quad = lane >> 4;

  const int sr = lane >> 3;                                // 0..7
  const int sc = ((lane & 7) ^ (lane >> 3)) * 8;           // bf16 offset in 64-K slab

  f32x4 acc[2][4] = {};

  for (int k0 = 0; k0 < K; k0 += 64) {
    __syncthreads();
#pragma unroll
    for (int j = 0; j < 2; j++) {
      const int rbase = wave * 16 + j * 8;
      gload16(A + (size_t)(m0 + rbase + sr) * K + k0 + sc, &As[rbase * 64]);
    }
#pragma unroll
    for (int j = 0; j < 4; j++) {
      const int rbase = wave * 32 + j * 8;
      gload16(Bt + (size_t)(n0 + rbase + sr) * K + k0 + sc, &Bs[rbase * 64]);
    }
    __syncthreads();
#pragma unroll
    for (int kh2 = 0; kh2 < 2; kh2++) {
      const int fo = ((kh2 * 4 + quad) ^ (lr & 7)) * 8;  // swizzled chunk offset
      bf16x8 af[2], bfr[4];
#pragma unroll
      for (int mt = 0; mt < 2; mt++)
        af[mt] = *(const bf16x8*)(&As[(wm + mt * 16 + lr) * 64 + fo]);
#pragma unroll
      for (int nt = 0; nt < 4; nt++)
        bfr[nt] = *(const bf16x8*)(&Bs[(wn + nt * 16 + lr) * 64 + fo]);
#pragma unroll
      for (int mt = 0; mt < 2; mt++)
#pragma unroll
        for (int nt = 0; nt < 4; nt++)
          acc[mt][nt] = __builtin_amdgcn_mfma_f32_16x16x32_bf16(af[mt], bfr[nt], acc[mt][nt], 0, 0, 0);
    }
  }

  if (QKV && n0 >= DMODEL + DKV) {
    // V-region: transpose through LDS -> coalesced stores to Vtb[n][m]
    __syncthreads();
#pragma unroll
    for (int nt = 0; nt < 4; nt++) {
      const int nrel = wn + nt * 16 + lr;
      const float b = bv[n0 - DMODEL - DKV + nrel];
#pragma unroll
      for (int mt = 0; mt < 2; mt++)
#pragma unroll
        for (int r = 0; r < 4; r++) {
          const int mrel = wm + mt * 16 + quad * 4 + r;
          Bs[nrel * 64 + mrel] = (bf16)((acc[mt][nt][r] + b) * mkf[m0 + mrel]);
        }
    }
    __syncthreads();
    const int row = t >> 1;           // 0..127
    const int hh = (t & 1) * 32;      // half-row of 64
#pragma unroll
    for (int j = 0; j < 4; j++) {
      *(uint4*)(Vtb + (size_t)(n0 - DMODEL - DKV + row) * S_LEN + m0 + hh + j * 8) =
          *(const uint4*)(&Bs[row * 64 + hh + j * 8]);
    }
    return;
  }

#pragma unroll
  for (int nt = 0; nt < 4; nt++) {
    const int n = n0 + wn + nt * 16 + lr;
    if (QKV) {
      if (n < DMODEL) {
        const float b = bq[n];
#pragma unroll
        for (int mt = 0; mt < 2; mt++)
#pragma unroll
          for (int r = 0; r < 4; r++) {
            const int m = m0 + wm + mt * 16 + quad * 4 + r;
            Qb[(size_t)m * DMODEL + n] = (bf16)((acc[mt][nt][r] + b) * QSCALE);
          }
      } else {
        const float b = bk[n - DMODEL];
#pragma unroll
        for (int mt = 0; mt < 2; mt++)
#pragma unroll
          for (int r = 0; r < 4; r++) {
            const int m = m0 + wm + mt * 16 + quad * 4 + r;
            Kb[(size_t)m * DKV + (n - DMODEL)] = (bf16)(acc[mt][nt][r] + b);
          }
      }
    } else {
      const float b = bo[n];
#pragma unroll
      for (int mt = 0; mt < 2; mt++)
#pragma unroll
        for (int r = 0; r < 4; r++) {
          const int m = m0 + wm + mt * 16 + quad * 4 + r;
          Co[(size_t)m * N + n] = acc[mt][nt][r] + b;
        }
    }
  }
}

// ---------------- flash attention: grid kv-split x2, single-buffer DMA ----------------
// grid: (S/128 * 2, H); block x = (qblock<<1)|half. Each block covers 2048 keys
// (16 kv-iters), 3 blocks/CU (42 KB LDS) vs the old grid-capped 2. Unnormalized
// fp32 partials (o, l) to workspace; combine kernel divides. Partials are
// additive because softmax is unnormalized exp2 (no online max needed).
__global__ __launch_bounds__(256) void flash_attn(
    const bf16* __restrict__ Q, const bf16* __restrict__ K,
    const bf16* __restrict__ Vt, const bf16* __restrict__ mkb,
    float* __restrict__ op, float* __restrict__ lp) {
  const int h = blockIdx.y;
  const int kvh = h >> 2;
  const int q0 = (blockIdx.x >> 1) * 128;
  const int half = blockIdx.x & 1;
  const int kvbase = half * (S_LEN / 2);
  const int t = threadIdx.x;
  const int lane = t & 63;
  const int wave = t >> 6;
  const int lr = lane & 15;
  const int quad = lane >> 4;

  __shared__ bf16 Ks[128 * 64];   // 16 KB, XOR-swizzled
  __shared__ bf16 Vs[64 * 128];   // 16 KB, XOR-swizzled
  __shared__ bf16 Ps[4][32][36];  // 9 KB, per-wave private round-trip

  bf16x8 aq[2][2];
#pragma unroll
  for (int qt = 0; qt < 2; qt++) {
    const int qrow = q0 + wave * 32 + qt * 16 + lr;
    aq[qt][0] = *(const bf16x8*)(Q + (size_t)qrow * DMODEL + h * HDK + quad * 8);
    aq[qt][1] = *(const bf16x8*)(Q + (size_t)qrow * DMODEL + h * HDK + 32 + quad * 8);
  }

  const bf16* Kg = K + kvh * HDK;
  const bf16* Vg = Vt + (size_t)kvh * HDK * S_LEN;
  const int krl = lane >> 3;
  const int kgc = ((lane & 7) ^ (lane >> 3)) * 8;
  const int vrl = lane >> 4;

  f32x4 o_acc[2][4] = {};
  f32x4 l_acc[2] = {};

  for (int kv0 = kvbase; kv0 < kvbase + S_LEN / 2; kv0 += 128) {
    __syncthreads();  // previous tile's LDS reads complete
#pragma unroll
    for (int j = 0; j < 4; j++) {
      const int rb = wave * 32 + j * 8;
      gload16(Kg + (size_t)(kv0 + rb + krl) * DKV + kgc, &Ks[rb * 64]);
    }
#pragma unroll
    for (int j = 0; j < 4; j++) {
      const int rb = wave * 16 + j * 4;
      const int g = ((lane & 15) ^ (j * 4 + vrl)) * 8;
      gload16(Vg + (size_t)(rb + vrl) * S_LEN + kv0 + g, &Vs[rb * 128]);
    }
    __syncthreads();  // DMA drained (vmcnt(0) before s_barrier)

#pragma unroll
    for (int kc = 0; kc < 4; kc++) {
      bf16x8 ak[2][2];
#pragma unroll
      for (int ntl = 0; ntl < 2; ntl++) {
        const int krow = kc * 32 + ntl * 16 + lr;
        ak[ntl][0] = *(const bf16x8*)(&Ks[krow * 64 + ((quad) ^ (lr & 7)) * 8]);
        ak[ntl][1] = *(const bf16x8*)(&Ks[krow * 64 + ((4 + quad) ^ (lr & 7)) * 8]);
      }
      // S^T = K @ Q^T : C-layout col=qrow(lane&15), row=key(quad*4+r)
#pragma unroll
      for (int qt = 0; qt < 2; qt++) {
#pragma unroll
        for (int ntl = 0; ntl < 2; ntl++) {
          f32x4 s = {};
          s = __builtin_amdgcn_mfma_f32_16x16x32_bf16(ak[ntl][0], aq[qt][0], s, 0, 0, 0);
          s = __builtin_amdgcn_mfma_f32_16x16x32_bf16(ak[ntl][1], aq[qt][1], s, 0, 0, 0);
          bf16 p4[4];
#pragma unroll
          for (int r = 0; r < 4; r++) p4[r] = (bf16)__builtin_amdgcn_exp2f(s[r]);
          *(uint2*)(&Ps[wave][qt * 16 + lr][ntl * 16 + quad * 4]) = *(uint2*)p4;
        }
      }
      bf16x8 bvf[4];
#pragma unroll
      for (int ntv = 0; ntv < 4; ntv++) {
        const int vrow = ntv * 16 + lr;
        bvf[ntv] = *(const bf16x8*)(&Vs[vrow * 128 + ((kc * 4 + quad) ^ lr) * 8]);
      }
      const bf16x8 mkfv = *(const bf16x8*)(mkb + kv0 + kc * 32 + quad * 8);
#pragma unroll
      for (int qt = 0; qt < 2; qt++) {
        bf16x8 ap = *(const bf16x8*)(&Ps[wave][qt * 16 + lr][quad * 8]);
#pragma unroll
        for (int ntv = 0; ntv < 4; ntv++)
          o_acc[qt][ntv] = __builtin_amdgcn_mfma_f32_16x16x32_bf16(ap, bvf[ntv], o_acc[qt][ntv], 0, 0, 0);
        l_acc[qt] = __builtin_amdgcn_mfma_f32_16x16x32_bf16(ap, mkfv, l_acc[qt], 0, 0, 0);
      }
    }
  }

  // epilogue: fp32 partials. l is lane-uniform across lr (mask B bcast) -> lr==0 writes.
  float* opb = op + (size_t)half * S_LEN * DMODEL;
#pragma unroll
  for (int qt = 0; qt < 2; qt++) {
#pragma unroll
    for (int r = 0; r < 4; r++) {
      const int row = q0 + wave * 32 + qt * 16 + quad * 4 + r;
#pragma unroll
      for (int ntv = 0; ntv < 4; ntv++)
        opb[(size_t)row * DMODEL + h * HDK + ntv * 16 + lr] = o_acc[qt][ntv][r];
      if (lr == 0) lp[((size_t)half * S_LEN + row) * NHEADS + h] = l_acc[qt][r];
    }
  }
}

// ---------------- combine: Ob = (o0+o1)/(l0+l1), bf16 ----------------
__global__ __launch_bounds__(256) void combine(
    const float* __restrict__ op, const float* __restrict__ lp,
    bf16* __restrict__ Ob) {
  const int i = (blockIdx.x * 256 + (int)threadIdx.x) * 8;
  const int row = i >> 10;
  const int h = (i & 1023) >> 6;
  const float l = lp[(size_t)row * NHEADS + h] +
                  lp[((size_t)S_LEN + row) * NHEADS + h];
  const float inv = 1.0f / l;
  const float* p0 = op + i;
  const float* p1 = op + (size_t)S_LEN * DMODEL + i;
  float4 a0 = *(const float4*)(p0);
  float4 a1 = *(const float4*)(p0 + 4);
  float4 b0 = *(const float4*)(p1);
  float4 b1 = *(const float4*)(p1 + 4);
  bf16 o[8] = {(bf16)((a0.x + b0.x) * inv), (bf16)((a0.y + b0.y) * inv),
               (bf16)((a0.z + b0.z) * inv), (bf16)((a0.w + b0.w) * inv),
               (bf16)((a1.x + b1.x) * inv), (bf16)((a1.y + b1.y) * inv),
               (bf16)((a1.z + b1.z) * inv), (bf16)((a1.w + b1.w) * inv)};
  *(uint4*)(Ob + i) = *(uint4*)o;
}

// ---------------- launch ----------------
extern "C" void kernel_launch(void* const* d_in, const int* in_sizes, int n_in,
                              void* d_out, int out_size, void* d_ws, size_t ws_size,
                              hipStream_t stream) {
  const float* x = (const float*)d_in[0];
  const int* mask = (const int*)d_in[1];
  const float* Wq = (const float*)d_in[2];
  const float* bq = (const float*)d_in[3];
  const float* Wk = (const float*)d_in[4];
  const float* bk = (const float*)d_in[5];
  const float* Wv = (const float*)d_in[6];
  const float* bv = (const float*)d_in[7];
  const float* Wo = (const float*)d_in[8];
  const float* bo = (const float*)d_in[9];
  float* out = (float*)d_out;

  char* w = (char*)d_ws;
  bf16* xb  = (bf16*)w; w += (size_t)S_LEN * DMODEL * 2;
  bf16* Wqt = (bf16*)w; w += (size_t)DMODEL * DMODEL * 2;  // packed B rows 0..1023
  bf16* Wkt = (bf16*)w; w += (size_t)DKV * DMODEL * 2;     // rows 1024..1279
  bf16* Wvt = (bf16*)w; w += (size_t)DKV * DMODEL * 2;     // rows 1280..1535
  bf16* Wot = (bf16*)w; w += (size_t)DMODEL * DMODEL * 2;
  bf16* Qb  = (bf16*)w; w += (size_t)S_LEN * DMODEL * 2;
  bf16* Kb  = (bf16*)w; w += (size_t)S_LEN * DKV * 2;
  bf16* Vtb = (bf16*)w; w += (size_t)DKV * S_LEN * 2;
  bf16* Ob  = (bf16*)w; w += (size_t)S_LEN * DMODEL * 2;
  float* mkf = (float*)w; w += (size_t)S_LEN * 4;
  bf16* mkb = (bf16*)w; w += (size_t)S_LEN * 2;
  w = (char*)(((uintptr_t)w + 255) & ~(uintptr_t)255);
  float* op = (float*)w; w += (size_t)2 * S_LEN * DMODEL * 4;  // 33.5 MB partial o
  float* lp = (float*)w; w += (size_t)2 * S_LEN * NHEADS * 4;  // 512 KB partial l

  // fused prep (1 dispatch): transposes + x convert + mask
  prep<<<dim3(32, 32, 6), 256, 0, stream>>>(
      x, mask, Wq, Wk, Wv, Wo, xb, mkf, mkb, Wqt, Wkt, Wvt, Wot);

  // fused QKV projection (packed N = 1536), XCD-scheduled 1D grid 768
  gemm_ld<1><<<dim3((S_LEN / 64) * (NTOT / 128)), 256, 0, stream>>>(
      xb, Wqt, S_LEN, NTOT, DMODEL, NTOT / 128, bq, bk, bv, mkf, Qb, Kb, Vtb,
      nullptr, nullptr);

  // attention: kv-split x2 -> 1024 blocks, partials to workspace
  flash_attn<<<dim3((S_LEN / 128) * 2, NHEADS), 256, 0, stream>>>(
      Qb, Kb, Vtb, mkb, op, lp);
  combine<<<dim3(S_LEN * DMODEL / (256 * 8)), 256, 0, stream>>>(op, lp, Ob);

  // output projection (fp32 out), XCD-scheduled 1D grid 512
  gemm_ld<0><<<dim3((S_LEN / 64) * (DMODEL / 128)), 256, 0, stream>>>(
      Ob, Wot, S_LEN, DMODEL, DMODEL, DMODEL / 128, nullptr, nullptr, nullptr,
      nullptr, nullptr, nullptr, nullptr, bo, out);
}